// Round 3
// baseline (440.799 us; speedup 1.0000x reference)
//
#include <hip/hip_runtime.h>

// Native vector type for vector stores (works with __builtin_nontemporal_* too).
typedef float f32x4 __attribute__((ext_vector_type(4)));

// ---------------- Diagnostic marker: neither input mapping validated ----------------
__global__ void bad_map_marker(float* out) {
    if (threadIdx.x == 0 && blockIdx.x == 0) out[0] = 1.0e6f;
}

// ---------------- Tail: LN1(64)+ReLU -> L2(64,32) -> LN2+ReLU -> L3(32,D) ----------------
__device__ __forceinline__ void mlp_tail_compute(float* h, float* pr, int D,
        const float* __restrict__ g1, const float* __restrict__ be1,
        const float* __restrict__ W2, const float* __restrict__ b2,
        const float* __restrict__ g2, const float* __restrict__ be2,
        const float* __restrict__ W3, const float* __restrict__ b3) {
    float s = 0.f, ss = 0.f;
    #pragma unroll
    for (int d = 0; d < 64; ++d) { s += h[d]; ss += h[d] * h[d]; }
    float mu  = s * (1.f / 64.f);
    float inv = rsqrtf(ss * (1.f / 64.f) - mu * mu + 1e-5f);
    #pragma unroll
    for (int d = 0; d < 64; ++d)
        h[d] = fmaxf((h[d] - mu) * inv * g1[d] + be1[d], 0.f);

    // Linear(64,32) — lane-uniform weight addresses (L1 broadcast)
    float a2[32];
    const float4* w2v = (const float4*)W2;
    #pragma unroll
    for (int n = 0; n < 32; ++n) a2[n] = b2[n];
    for (int k = 0; k < 64; ++k) {
        float hk = h[k];
        #pragma unroll
        for (int q = 0; q < 8; ++q) {
            float4 w = w2v[k * 8 + q];
            a2[4 * q + 0] += hk * w.x;
            a2[4 * q + 1] += hk * w.y;
            a2[4 * q + 2] += hk * w.z;
            a2[4 * q + 3] += hk * w.w;
        }
    }
    s = 0.f; ss = 0.f;
    #pragma unroll
    for (int n = 0; n < 32; ++n) { s += a2[n]; ss += a2[n] * a2[n]; }
    mu  = s * (1.f / 32.f);
    inv = rsqrtf(ss * (1.f / 32.f) - mu * mu + 1e-5f);
    #pragma unroll
    for (int n = 0; n < 32; ++n)
        a2[n] = fmaxf((a2[n] - mu) * inv * g2[n] + be2[n], 0.f);

    for (int d = 0; d < D; ++d) pr[d] = b3[d];
    for (int k = 0; k < 32; ++k) {
        float hk = a2[k];
        const float* wr = W3 + k * D;
        for (int d = 0; d < D; ++d) pr[d] += hk * wr[d];
    }
}

// Coalesced diag-embed epilogue (fused fallback path), 256 pairs/block.
__device__ __forceinline__ void store_diag16_f32_256(const float* pp, float* out, int P) {
    const int t = threadIdx.x;
    float4* outv = (float4*)out + (size_t)blockIdx.x * 16384;
    const int pbase = blockIdx.x * 256;
    #pragma unroll 8
    for (int it = 0; it < 64; ++it) {
        int g = it * 256 + t;
        int pl = g >> 6;
        int rem = g & 63;
        int d = rem >> 2;
        int c4 = rem & 3;
        float val = pp[pl * 17 + d];
        bool on = (d >> 2) == c4;
        float4 v;
        v.x = (on && (d & 3) == 0) ? val : 0.f;
        v.y = (on && (d & 3) == 1) ? val : 0.f;
        v.z = (on && (d & 3) == 2) ? val : 0.f;
        v.w = (on && (d & 3) == 3) ? val : 0.f;
        if (pbase + pl < P) outv[g] = v;
    }
}

// ---------------- Fast path stage 1 (F==128): tiled GEMM, Y[e][n] ----------------
// 16 edges x 128 cols per block -> 1250 blocks (occupancy); thread: 1 edge x 8 cols.
__global__ __launch_bounds__(256)
void precompute_y(const float* __restrict__ ef, const float* __restrict__ W1,
                  const float* __restrict__ b1, float* __restrict__ Y, int E) {
    __shared__ __align__(16) float el[16 * 132];   // 8448 B
    const int t = threadIdx.x;
    const int ebase = blockIdx.x * 16;

    for (int idx = t; idx < 512; idx += 256) {
        int er = idx >> 5, ec = idx & 31;
        if (ebase + er < E)
            *((float4*)(el + er * 132) + ec) =
                *((const float4*)(ef + (size_t)(ebase + er) * 128) + ec);
    }
    __syncthreads();

    const int eg  = t & 15;
    const int cgi = t >> 4;
    const int half  = cgi >> 3;
    const int col64 = (cgi & 7) * 8;

    float acc[8];
    #pragma unroll
    for (int c = 0; c < 8; ++c) acc[c] = 0.f;

    const float* wbase = W1 + (size_t)half * 128 * 64 + col64;
    const float* erow  = el + eg * 132;
    #pragma unroll 4
    for (int k = 0; k < 128; ++k) {
        float4 w0 = *(const float4*)(wbase + (size_t)k * 64);
        float4 w1 = *(const float4*)(wbase + (size_t)k * 64 + 4);
        float a = erow[k];
        acc[0] += a * w0.x; acc[1] += a * w0.y;
        acc[2] += a * w0.z; acc[3] += a * w0.w;
        acc[4] += a * w1.x; acc[5] += a * w1.y;
        acc[6] += a * w1.z; acc[7] += a * w1.w;
    }

    #pragma unroll
    for (int c = 0; c < 8; ++c) acc[c] += (half == 0) ? b1[col64 + c] : 0.f;

    int e = ebase + eg;
    if (e < E) {
        float* dst = Y + (size_t)e * 128 + half * 64 + col64;
        *(float4*)(dst)     = make_float4(acc[0], acc[1], acc[2], acc[3]);
        *(float4*)(dst + 4) = make_float4(acc[4], acc[5], acc[6], acc[7]);
    }
}

// ---------------- Fast path stage 2a: gather + MLP -> params[P,16] ----------------
// Decoupled from the big output write so the VGPR-heavy, gather-latency-bound phase
// doesn't throttle the streaming-store phase's occupancy.
__global__ __launch_bounds__(256)
void pairs_params(const int* __restrict__ pi, const int* __restrict__ pj,
                  const float* __restrict__ Y,
                  const float* __restrict__ g1, const float* __restrict__ be1,
                  const float* __restrict__ W2, const float* __restrict__ b2,
                  const float* __restrict__ g2, const float* __restrict__ be2,
                  const float* __restrict__ W3, const float* __restrict__ b3,
                  float* __restrict__ params, int P) {
    __shared__ float pp[256 * 17];
    const int t = threadIdx.x;
    int p = blockIdx.x * 256 + t;
    int pc = p < P ? p : P - 1;
    int i = pi[pc], j = pj[pc];
    const float4* y1 = (const float4*)(Y + (size_t)i * 128);
    const float4* y2 = (const float4*)(Y + (size_t)j * 128 + 64);
    float h[64];
    #pragma unroll
    for (int q = 0; q < 16; ++q) {
        float4 a = y1[q], b = y2[q];
        h[4 * q + 0] = a.x + b.x;
        h[4 * q + 1] = a.y + b.y;
        h[4 * q + 2] = a.z + b.z;
        h[4 * q + 3] = a.w + b.w;
    }
    float pr[16];
    mlp_tail_compute(h, pr, 16, g1, be1, W2, b2, g2, be2, W3, b3);
    #pragma unroll
    for (int d = 0; d < 16; ++d) pp[t * 17 + d] = pr[d];
    __syncthreads();

    // Coalesced write of 256x16 floats = 1024 float4 per block.
    float4* pv = (float4*)params + (size_t)blockIdx.x * 1024;
    const int pbase = blockIdx.x * 256;
    #pragma unroll
    for (int it = 0; it < 4; ++it) {
        int c = it * 256 + t;
        int pl = c >> 2;         // local pair
        int q  = c & 3;          // float4 within pair
        const float* src = pp + pl * 17 + q * 4;
        float4 v = make_float4(src[0], src[1], src[2], src[3]);
        if (pbase + pl < P) pv[c] = v;
    }
}

// ---------------- Fast path stage 2b: streaming diag-embed expand ----------------
// Pure write kernel: ~8 VGPRs -> max occupancy -> should run at fill-like BW.
// out chunk g (float4): pl=g>>6, rem=g&63, row d=rem>>2, col-group c4=rem&3.
__global__ __launch_bounds__(256)
void diag_expand(const float* __restrict__ params, float* __restrict__ out,
                 long total4) {
    f32x4* outv = (f32x4*)out;
    const size_t stride = (size_t)gridDim.x * 256;
    for (size_t g = (size_t)blockIdx.x * 256 + threadIdx.x; g < (size_t)total4;
         g += stride) {
        int pl  = (int)(g >> 6);
        int rem = (int)(g & 63);
        int d   = rem >> 2;
        int c4  = rem & 3;
        float val = params[(size_t)pl * 16 + d];
        bool on = (d >> 2) == c4;
        f32x4 v;
        v.x = (on && (d & 3) == 0) ? val : 0.f;
        v.y = (on && (d & 3) == 1) ? val : 0.f;
        v.z = (on && (d & 3) == 2) ? val : 0.f;
        v.w = (on && (d & 3) == 3) ? val : 0.f;
        outv[g] = v;
    }
}

// ---------------- Fused fallback (ws too small for params): R7 structure ----------------
__global__ __launch_bounds__(256)
void sheaf_pairs(const int* __restrict__ pi, const int* __restrict__ pj,
                 const float* __restrict__ Y,
                 const float* __restrict__ g1, const float* __restrict__ be1,
                 const float* __restrict__ W2, const float* __restrict__ b2,
                 const float* __restrict__ g2, const float* __restrict__ be2,
                 const float* __restrict__ W3, const float* __restrict__ b3,
                 float* __restrict__ out, int P) {
    __shared__ float pp[256 * 17];
    int p = blockIdx.x * 256 + threadIdx.x;
    int pc = p < P ? p : P - 1;
    int i = pi[pc], j = pj[pc];
    const float4* y1 = (const float4*)(Y + (size_t)i * 128);
    const float4* y2 = (const float4*)(Y + (size_t)j * 128 + 64);
    float h[64];
    #pragma unroll
    for (int q = 0; q < 16; ++q) {
        float4 a = y1[q], b = y2[q];
        h[4 * q + 0] = a.x + b.x;
        h[4 * q + 1] = a.y + b.y;
        h[4 * q + 2] = a.z + b.z;
        h[4 * q + 3] = a.w + b.w;
    }
    float pr[16];
    mlp_tail_compute(h, pr, 16, g1, be1, W2, b2, g2, be2, W3, b3);
    #pragma unroll
    for (int d = 0; d < 16; ++d) pp[threadIdx.x * 17 + d] = pr[d];
    __syncthreads();
    store_diag16_f32_256(pp, out, P);
}

// ---------------- Generic fallback: runtime F, D (<=32) ----------------
__global__ __launch_bounds__(256)
void sheaf_generic(const float* __restrict__ ef,
                   const int* __restrict__ pi, const int* __restrict__ pj,
                   const float* __restrict__ W1, const float* __restrict__ b1,
                   const float* __restrict__ g1, const float* __restrict__ be1,
                   const float* __restrict__ W2, const float* __restrict__ b2,
                   const float* __restrict__ g2, const float* __restrict__ be2,
                   const float* __restrict__ W3, const float* __restrict__ b3,
                   float* __restrict__ out, int P, int F, int D) {
    __shared__ float pp[256 * 17];
    int p = blockIdx.x * 256 + threadIdx.x;
    int pc = p < P ? p : P - 1;
    int i = pi[pc], j = pj[pc];
    const float* efi = ef + (size_t)i * F;
    const float* efj = ef + (size_t)j * F;
    float h[64];
    #pragma unroll
    for (int n = 0; n < 64; ++n) h[n] = b1[n];
    for (int k = 0; k < F; ++k) {
        float ei = efi[k];
        float ej = efj[k];
        const float* wi = W1 + (size_t)k * 64;
        const float* wj = W1 + (size_t)(F + k) * 64;
        #pragma unroll
        for (int n = 0; n < 64; ++n) h[n] += ei * wi[n] + ej * wj[n];
    }
    float pr[32];
    mlp_tail_compute(h, pr, D, g1, be1, W2, b2, g2, be2, W3, b3);

    if (D == 16) {
        #pragma unroll
        for (int d = 0; d < 16; ++d) pp[threadIdx.x * 17 + d] = pr[d];
        __syncthreads();
        store_diag16_f32_256(pp, out, P);
    } else {
        if (p < P) {
            float* po = out + (size_t)p * D * D;
            for (int r = 0; r < D; ++r) {
                float dv = pr[r];
                for (int c = 0; c < D; ++c) po[r * D + c] = (r == c) ? dv : 0.f;
            }
        }
    }
}

// ---------------- Host side: derive ALL dims from in_sizes/out_size ----------------
struct Map { int ef, pi, pj, w1, b1, g1, be1, w2, b2, g2, be2, w3, b3; };

static bool validate_map(const Map& m, const int* s, int n_in, long out_size,
                         int* Fo, int* Eo, int* Do, int* Po) {
    if (n_in < 13) return false;
    if (s[m.b1] != 64 || s[m.g1] != 64 || s[m.be1] != 64) return false;
    if (s[m.b2] != 32 || s[m.g2] != 32 || s[m.be2] != 32) return false;
    if (s[m.w2] != 64 * 32) return false;
    long w1 = s[m.w1];
    if (w1 <= 0 || (w1 % 128) != 0) return false;       // W1 = (2F, 64)
    long F = w1 / 128;
    if (F <= 0) return false;
    int D = s[m.b3];
    if (D <= 0 || D > 32) return false;
    if (s[m.w3] != 32 * D) return false;
    long P = s[m.pi];
    if (P <= 0 || s[m.pj] != P) return false;
    long ef = s[m.ef];
    if (ef <= 0 || (ef % F) != 0) return false;
    long E = ef / F;
    if (out_size != P * D * D) return false;
    *Fo = (int)F; *Eo = (int)E; *Do = D; *Po = (int)P;
    return true;
}

extern "C" void kernel_launch(void* const* d_in, const int* in_sizes, int n_in,
                              void* d_out, int out_size, void* d_ws, size_t ws_size,
                              hipStream_t stream) {
    const Map pos   = {0, 1, 2, 3, 4, 5, 6, 7, 8, 9, 10, 11, 12};
    const Map alpha = {8, 11, 12, 0, 3, 9, 6, 1, 4, 10, 7, 2, 5};

    int F = 0, E = 0, D = 0, P = 0;
    Map m;
    if (validate_map(pos, in_sizes, n_in, (long)out_size, &F, &E, &D, &P)) {
        m = pos;
    } else if (validate_map(alpha, in_sizes, n_in, (long)out_size, &F, &E, &D, &P)) {
        m = alpha;
    } else {
        bad_map_marker<<<dim3(1), dim3(64), 0, stream>>>((float*)d_out);
        return;
    }

    const float* ef  = (const float*)d_in[m.ef];
    const int*   pi  = (const int*)d_in[m.pi];
    const int*   pj  = (const int*)d_in[m.pj];
    const float* W1  = (const float*)d_in[m.w1];
    const float* b1  = (const float*)d_in[m.b1];
    const float* g1  = (const float*)d_in[m.g1];
    const float* be1 = (const float*)d_in[m.be1];
    const float* W2  = (const float*)d_in[m.w2];
    const float* b2  = (const float*)d_in[m.b2];
    const float* g2  = (const float*)d_in[m.g2];
    const float* be2 = (const float*)d_in[m.be2];
    const float* W3  = (const float*)d_in[m.w3];
    const float* b3  = (const float*)d_in[m.b3];
    float* out = (float*)d_out;

    const size_t y_bytes = (size_t)E * 128 * 4;
    const size_t p_bytes = (size_t)P * 16 * 4;

    if (F == 128 && D == 16 && ws_size >= y_bytes) {
        float* Y = (float*)d_ws;
        precompute_y<<<dim3((E + 15) / 16), dim3(256), 0, stream>>>(ef, W1, b1, Y, E);
        if (ws_size >= y_bytes + p_bytes) {
            // Decoupled: compute params, then stream the diag-embed at write BW.
            float* params = (float*)((char*)d_ws + y_bytes);
            pairs_params<<<dim3((P + 255) / 256), dim3(256), 0, stream>>>(
                pi, pj, Y, g1, be1, W2, b2, g2, be2, W3, b3, params, P);
            long total4 = (long)P * 64;   // float4 chunks in out
            int blocks = 3072;
            diag_expand<<<dim3(blocks), dim3(256), 0, stream>>>(params, out, total4);
        } else {
            sheaf_pairs<<<dim3((P + 255) / 256), dim3(256), 0, stream>>>(
                pi, pj, Y, g1, be1, W2, b2, g2, be2, W3, b3, out, P);
        }
    } else {
        sheaf_generic<<<dim3((P + 255) / 256), dim3(256), 0, stream>>>(
            ef, pi, pj, W1, b1, g1, be1, W2, b2, g2, be2, W3, b3, out, P, F, D);
    }
}

// Round 4
// 389.420 us; speedup vs baseline: 1.1319x; 1.1319x over previous
//
#include <hip/hip_runtime.h>

// ---------------- Diagnostic marker: neither input mapping validated ----------------
__global__ void bad_map_marker(float* out) {
    if (threadIdx.x == 0 && blockIdx.x == 0) out[0] = 1.0e6f;
}

// ---------------- Tail: LN1(64)+ReLU -> L2(64,32) -> LN2+ReLU -> L3(32,D) ----------------
// Weight pointers may be LDS (broadcast reads: free for lane-uniform addresses,
// no vmcnt) or global (fallback path).
__device__ __forceinline__ void mlp_tail_compute(float* h, float* pr, int D,
        const float* g1, const float* be1,
        const float* W2, const float* b2,
        const float* g2, const float* be2,
        const float* W3, const float* b3) {
    float s = 0.f, ss = 0.f;
    #pragma unroll
    for (int d = 0; d < 64; ++d) { s += h[d]; ss += h[d] * h[d]; }
    float mu  = s * (1.f / 64.f);
    float inv = rsqrtf(ss * (1.f / 64.f) - mu * mu + 1e-5f);
    #pragma unroll
    for (int d = 0; d < 64; ++d)
        h[d] = fmaxf((h[d] - mu) * inv * g1[d] + be1[d], 0.f);

    // Linear(64,32)
    float a2[32];
    const float4* w2v = (const float4*)W2;
    #pragma unroll
    for (int n = 0; n < 32; ++n) a2[n] = b2[n];
    for (int k = 0; k < 64; ++k) {
        float hk = h[k];
        #pragma unroll
        for (int q = 0; q < 8; ++q) {
            float4 w = w2v[k * 8 + q];
            a2[4 * q + 0] += hk * w.x;
            a2[4 * q + 1] += hk * w.y;
            a2[4 * q + 2] += hk * w.z;
            a2[4 * q + 3] += hk * w.w;
        }
    }
    s = 0.f; ss = 0.f;
    #pragma unroll
    for (int n = 0; n < 32; ++n) { s += a2[n]; ss += a2[n] * a2[n]; }
    mu  = s * (1.f / 32.f);
    inv = rsqrtf(ss * (1.f / 32.f) - mu * mu + 1e-5f);
    #pragma unroll
    for (int n = 0; n < 32; ++n)
        a2[n] = fmaxf((a2[n] - mu) * inv * g2[n] + be2[n], 0.f);

    for (int d = 0; d < D; ++d) pr[d] = b3[d];
    for (int k = 0; k < 32; ++k) {
        float hk = a2[k];
        const float* wr = W3 + k * D;
        for (int d = 0; d < D; ++d) pr[d] += hk * wr[d];
    }
}

// Coalesced diag-embed epilogue, 256 pairs/block -> 16384 float4 chunks. Plain stores
// (measured: nontemporal stores were +10us vs plain on this path).
__device__ __forceinline__ void store_diag16_f32_256(const float* pp, float* out, int P) {
    const int t = threadIdx.x;
    float4* outv = (float4*)out + (size_t)blockIdx.x * 16384;
    const int pbase = blockIdx.x * 256;
    #pragma unroll 8
    for (int it = 0; it < 64; ++it) {
        int g = it * 256 + t;
        int pl = g >> 6;
        int rem = g & 63;
        int d = rem >> 2;
        int c4 = rem & 3;
        float val = pp[pl * 17 + d];
        bool on = (d >> 2) == c4;
        float4 v;
        v.x = (on && (d & 3) == 0) ? val : 0.f;
        v.y = (on && (d & 3) == 1) ? val : 0.f;
        v.z = (on && (d & 3) == 2) ? val : 0.f;
        v.w = (on && (d & 3) == 3) ? val : 0.f;
        if (pbase + pl < P) outv[g] = v;
    }
}

// ---------------- Fast path stage 1 (F==128): tiled GEMM, Y[e][n] ----------------
// R0 structure (64 edges x 128 cols, thread: 4 edges x 8 cols) — measured-good.
__global__ __launch_bounds__(256)
void precompute_y(const float* __restrict__ ef, const float* __restrict__ W1,
                  const float* __restrict__ b1, float* __restrict__ Y, int E) {
    __shared__ __align__(16) float el[64 * 132];   // 33792 B
    const int t = threadIdx.x;
    const int ebase = blockIdx.x * 64;

    for (int idx = t; idx < 2048; idx += 256) {
        int er = idx >> 5, ec = idx & 31;
        if (ebase + er < E)
            *((float4*)(el + er * 132) + ec) =
                *((const float4*)(ef + (size_t)(ebase + er) * 128) + ec);
    }
    __syncthreads();

    const int cg = t & 15;
    const int eg = t >> 4;
    const int half = cg >> 3;
    const int col64 = (cg & 7) * 8;

    float acc[4][8];
    #pragma unroll
    for (int i = 0; i < 4; ++i)
        #pragma unroll
        for (int c = 0; c < 8; ++c) acc[i][c] = 0.f;

    const float* wbase = W1 + (size_t)half * 128 * 64 + col64;
    #pragma unroll 4
    for (int k = 0; k < 128; ++k) {
        float4 w0 = *(const float4*)(wbase + (size_t)k * 64);
        float4 w1 = *(const float4*)(wbase + (size_t)k * 64 + 4);
        float wv[8] = {w0.x, w0.y, w0.z, w0.w, w1.x, w1.y, w1.z, w1.w};
        #pragma unroll
        for (int i = 0; i < 4; ++i) {
            float a = el[(eg * 4 + i) * 132 + k];
            #pragma unroll
            for (int c = 0; c < 8; ++c) acc[i][c] += a * wv[c];
        }
    }

    float bb[8];
    #pragma unroll
    for (int c = 0; c < 8; ++c) bb[c] = (half == 0) ? b1[col64 + c] : 0.f;
    #pragma unroll
    for (int i = 0; i < 4; ++i) {
        int e = ebase + eg * 4 + i;
        if (e < E) {
            float* dst = Y + (size_t)e * 128 + half * 64 + col64;
            #pragma unroll
            for (int c = 0; c < 8; ++c) dst[c] = acc[i][c] + bb[c];
        }
    }
}

// ---------------- Fast path stage 2: 1 thread/pair, weights staged in LDS ----------------
// CHANGE vs R0: W2/W3/g/b vectors staged into LDS once per block. Removes ~640
// lane-uniform global_load_dwordx4 per wave (L1/vmcnt pressure) in favor of
// broadcast ds_reads.
__global__ __launch_bounds__(256)
void sheaf_pairs(const int* __restrict__ pi, const int* __restrict__ pj,
                 const float* __restrict__ Y,
                 const float* __restrict__ g1, const float* __restrict__ be1,
                 const float* __restrict__ W2, const float* __restrict__ b2,
                 const float* __restrict__ g2, const float* __restrict__ be2,
                 const float* __restrict__ W3, const float* __restrict__ b3,
                 float* __restrict__ out, int P) {
    __shared__ float pp[256 * 17];
    __shared__ __align__(16) float w2s[64 * 32];
    __shared__ __align__(16) float w3s[32 * 16];
    __shared__ float g1s[64], be1s[64], b2s[32], g2s[32], be2s[32], b3s[16];

    const int t = threadIdx.x;
    int p = blockIdx.x * 256 + t;
    int pc = p < P ? p : P - 1;
    int i = pi[pc], j = pj[pc];
    const float4* y1 = (const float4*)(Y + (size_t)i * 128);
    const float4* y2 = (const float4*)(Y + (size_t)j * 128 + 64);
    float h[64];
    #pragma unroll
    for (int q = 0; q < 16; ++q) {
        float4 a = y1[q], b = y2[q];
        h[4 * q + 0] = a.x + b.x;
        h[4 * q + 1] = a.y + b.y;
        h[4 * q + 2] = a.z + b.z;
        h[4 * q + 3] = a.w + b.w;
    }

    // Stage all MLP-tail weights into LDS (once per block).
    {
        const float4* s2 = (const float4*)W2;      // 512 float4
        float4* d2 = (float4*)w2s;
        d2[t]       = s2[t];
        d2[t + 256] = s2[t + 256];
        if (t < 128) ((float4*)w3s)[t] = ((const float4*)W3)[t];   // 128 float4
        if (t < 64)                 { g1s[t] = g1[t]; be1s[t] = be1[t]; }
        else if (t < 96)            b2s[t - 64]   = b2[t - 64];
        else if (t < 128)           g2s[t - 96]   = g2[t - 96];
        else if (t < 160)           be2s[t - 128] = be2[t - 128];
        else if (t < 176)           b3s[t - 160]  = b3[t - 160];
    }
    __syncthreads();

    float pr[16];
    mlp_tail_compute(h, pr, 16, g1s, be1s, w2s, b2s, g2s, be2s, w3s, b3s);
    #pragma unroll
    for (int d = 0; d < 16; ++d) pp[t * 17 + d] = pr[d];
    __syncthreads();
    store_diag16_f32_256(pp, out, P);
}

// ---------------- Generic fallback: runtime F, D (<=32) ----------------
__global__ __launch_bounds__(256)
void sheaf_generic(const float* __restrict__ ef,
                   const int* __restrict__ pi, const int* __restrict__ pj,
                   const float* __restrict__ W1, const float* __restrict__ b1,
                   const float* __restrict__ g1, const float* __restrict__ be1,
                   const float* __restrict__ W2, const float* __restrict__ b2,
                   const float* __restrict__ g2, const float* __restrict__ be2,
                   const float* __restrict__ W3, const float* __restrict__ b3,
                   float* __restrict__ out, int P, int F, int D) {
    __shared__ float pp[256 * 17];
    int p = blockIdx.x * 256 + threadIdx.x;
    int pc = p < P ? p : P - 1;
    int i = pi[pc], j = pj[pc];
    const float* efi = ef + (size_t)i * F;
    const float* efj = ef + (size_t)j * F;
    float h[64];
    #pragma unroll
    for (int n = 0; n < 64; ++n) h[n] = b1[n];
    for (int k = 0; k < F; ++k) {
        float ei = efi[k];
        float ej = efj[k];
        const float* wi = W1 + (size_t)k * 64;
        const float* wj = W1 + (size_t)(F + k) * 64;
        #pragma unroll
        for (int n = 0; n < 64; ++n) h[n] += ei * wi[n] + ej * wj[n];
    }
    float pr[32];
    mlp_tail_compute(h, pr, D, g1, be1, W2, b2, g2, be2, W3, b3);

    if (D == 16) {
        #pragma unroll
        for (int d = 0; d < 16; ++d) pp[threadIdx.x * 17 + d] = pr[d];
        __syncthreads();
        store_diag16_f32_256(pp, out, P);
    } else {
        if (p < P) {
            float* po = out + (size_t)p * D * D;
            for (int r = 0; r < D; ++r) {
                float dv = pr[r];
                for (int c = 0; c < D; ++c) po[r * D + c] = (r == c) ? dv : 0.f;
            }
        }
    }
}

// ---------------- Host side: derive ALL dims from in_sizes/out_size ----------------
struct Map { int ef, pi, pj, w1, b1, g1, be1, w2, b2, g2, be2, w3, b3; };

static bool validate_map(const Map& m, const int* s, int n_in, long out_size,
                         int* Fo, int* Eo, int* Do, int* Po) {
    if (n_in < 13) return false;
    if (s[m.b1] != 64 || s[m.g1] != 64 || s[m.be1] != 64) return false;
    if (s[m.b2] != 32 || s[m.g2] != 32 || s[m.be2] != 32) return false;
    if (s[m.w2] != 64 * 32) return false;
    long w1 = s[m.w1];
    if (w1 <= 0 || (w1 % 128) != 0) return false;       // W1 = (2F, 64)
    long F = w1 / 128;
    if (F <= 0) return false;
    int D = s[m.b3];
    if (D <= 0 || D > 32) return false;
    if (s[m.w3] != 32 * D) return false;
    long P = s[m.pi];
    if (P <= 0 || s[m.pj] != P) return false;
    long ef = s[m.ef];
    if (ef <= 0 || (ef % F) != 0) return false;
    long E = ef / F;
    if (out_size != P * D * D) return false;
    *Fo = (int)F; *Eo = (int)E; *Do = D; *Po = (int)P;
    return true;
}

extern "C" void kernel_launch(void* const* d_in, const int* in_sizes, int n_in,
                              void* d_out, int out_size, void* d_ws, size_t ws_size,
                              hipStream_t stream) {
    const Map pos   = {0, 1, 2, 3, 4, 5, 6, 7, 8, 9, 10, 11, 12};
    const Map alpha = {8, 11, 12, 0, 3, 9, 6, 1, 4, 10, 7, 2, 5};

    int F = 0, E = 0, D = 0, P = 0;
    Map m;
    if (validate_map(pos, in_sizes, n_in, (long)out_size, &F, &E, &D, &P)) {
        m = pos;
    } else if (validate_map(alpha, in_sizes, n_in, (long)out_size, &F, &E, &D, &P)) {
        m = alpha;
    } else {
        bad_map_marker<<<dim3(1), dim3(64), 0, stream>>>((float*)d_out);
        return;
    }

    const float* ef  = (const float*)d_in[m.ef];
    const int*   pi  = (const int*)d_in[m.pi];
    const int*   pj  = (const int*)d_in[m.pj];
    const float* W1  = (const float*)d_in[m.w1];
    const float* b1  = (const float*)d_in[m.b1];
    const float* g1  = (const float*)d_in[m.g1];
    const float* be1 = (const float*)d_in[m.be1];
    const float* W2  = (const float*)d_in[m.w2];
    const float* b2  = (const float*)d_in[m.b2];
    const float* g2  = (const float*)d_in[m.g2];
    const float* be2 = (const float*)d_in[m.be2];
    const float* W3  = (const float*)d_in[m.w3];
    const float* b3  = (const float*)d_in[m.b3];
    float* out = (float*)d_out;

    const size_t y_bytes = (size_t)E * 128 * 4;

    if (F == 128 && D == 16 && ws_size >= y_bytes) {
        float* Y = (float*)d_ws;
        precompute_y<<<dim3((E + 63) / 64), dim3(256), 0, stream>>>(ef, W1, b1, Y, E);
        sheaf_pairs<<<dim3((P + 255) / 256), dim3(256), 0, stream>>>(
            pi, pj, Y, g1, be1, W2, b2, g2, be2, W3, b3, out, P);
    } else {
        sheaf_generic<<<dim3((P + 255) / 256), dim3(256), 0, stream>>>(
            ef, pi, pj, W1, b1, g1, be1, W2, b2, g2, be2, W3, b3, out, P, F, D);
    }
}